// Round 4
// baseline (440.907 us; speedup 1.0000x reference)
//
#include <hip/hip_runtime.h>
#include <hip/hip_bf16.h>
#include <cstdint>
#include <cstddef>

typedef __bf16 bf16;
typedef __bf16 bf16x8 __attribute__((ext_vector_type(8)));
typedef float f32x4 __attribute__((ext_vector_type(4)));

#define BATCH 8192
#define IN_DIM 2048
#define HID 2048
#define RANK 512
#define KDIM 4096    // IN+HID
#define NG 2048      // 4*RANK
#define CHUNK_ROWS 4096

// ---------------- helpers ----------------

__device__ __forceinline__ void gload16(const void* g, void* l) {
  __builtin_amdgcn_global_load_lds(
      (const __attribute__((address_space(1))) unsigned int*)g,
      (__attribute__((address_space(3))) unsigned int*)l, 16, 0, 0);
}

__device__ __forceinline__ float sigmoidf_(float x) {
  return 1.0f / (1.0f + __expf(-x));
}
__device__ __forceinline__ float tanhf_(float x) {
  return 1.0f - 2.0f / (__expf(2.0f * x) + 1.0f);
}

// Stage one 128-row x 64-col bf16 half-tile into linear LDS via global_load_lds,
// st-swizzle applied on the GLOBAL source address (inverse of the read swizzle;
// LDS dest stays linear — both-sides rule). 512 thr x 2 x 16B. vmcnt += 2/thread.
__device__ __forceinline__ void stage_half(const bf16* __restrict__ g0, int ld,
                                           int row0, int kcol, bf16* lbase, int tid) {
  const int wid = tid >> 6;
  #pragma unroll
  for (int q = 0; q < 2; ++q) {
    const int slot = q * 512 + tid;
    const int row = slot >> 3, cb = slot & 7;
    const int gcb = cb ^ (row & 7);
    gload16(g0 + (size_t)(row0 + row) * ld + kcol + gcb * 8,
            lbase + (size_t)(q * 64 + wid * 8) * 64);
  }
}

#define GBAR  __builtin_amdgcn_s_barrier()
#define LGKM0 asm volatile("s_waitcnt lgkmcnt(0)" ::: "memory")
#define VMC4  asm volatile("s_waitcnt vmcnt(4)" ::: "memory")

// Swizzled ds_read of one bf16x8 fragment. row&7 == lr&7 for all frag rows.
#define LD_B(BUFc)                                                                   \
  _Pragma("unroll") for (int j = 0; j < 4; ++j) {                                    \
    b[j][0] = *(const bf16x8*)(&Bls[BUFc][wn + j * 16 + lr][(lk ^ sw) * 8]);         \
    b[j][1] = *(const bf16x8*)(&Bls[BUFc][wn + j * 16 + lr][((4 | lk) ^ sw) * 8]);   \
  }
#define LD_A(BUFc, Q)                                                                \
  _Pragma("unroll") for (int ai = 0; ai < 2; ++ai) {                                 \
    a[ai][0] = *(const bf16x8*)(&Als[BUFc][wm + ((Q) * 2 + ai) * 16 + lr][(lk ^ sw) * 8]); \
    a[ai][1] = *(const bf16x8*)(&Als[BUFc][wm + ((Q) * 2 + ai) * 16 + lr][((4 | lk) ^ sw) * 8]); \
  }
#define MFMAQ(Q)                                                                     \
  _Pragma("unroll") for (int ai = 0; ai < 2; ++ai)                                   \
  _Pragma("unroll") for (int ks = 0; ks < 2; ++ks)                                   \
  _Pragma("unroll") for (int j = 0; j < 4; ++j)                                      \
    acc[(Q) * 2 + ai][j] = __builtin_amdgcn_mfma_f32_16x16x32_bf16(                  \
        a[ai][ks], b[j][ks], acc[(Q) * 2 + ai][j], 0, 0, 0);

#define PHASE(BUFc, Q, STAGE, TAILVM) \
  {                                   \
    if ((Q) == 0) { LD_B(BUFc); }     \
    LD_A(BUFc, Q);                    \
    STAGE;                            \
    GBAR;                             \
    LGKM0;                            \
    __builtin_amdgcn_s_setprio(1);    \
    MFMAQ(Q);                         \
    __builtin_amdgcn_s_setprio(0);    \
    TAILVM;                           \
    GBAR;                             \
  }

// 256x256 tile, BK=64, 8 waves (2M x 4N), double-buffered 128 KiB LDS,
// 8-phase interleave with counted vmcnt. NT = K/64 (power of two, >= 2).
template <int NT>
__device__ __forceinline__ void gemm_core(const bf16* __restrict__ A, int lda, int m0,
                                          const bf16* __restrict__ B, int ldb, int n0,
                                          bf16 (&Als)[2][256][64], bf16 (&Bls)[2][256][64],
                                          f32x4 (&acc)[8][4]) {
  const int tid = threadIdx.x;
  const int wid = tid >> 6, lane = tid & 63;
  const int wm = (wid >> 2) * 128, wn = (wid & 3) * 64;
  const int lr = lane & 15, lk = lane >> 4;
  const int sw = lr & 7;
  bf16x8 a[2][2], b[4][2];

  #pragma unroll
  for (int i = 0; i < 8; ++i)
    #pragma unroll
    for (int j = 0; j < 4; ++j) acc[i][j] = (f32x4){0.f, 0.f, 0.f, 0.f};

  // Prologue: K-tile 0 (A+B -> buf0), B of K-tile 1 -> buf1.  12 loads.
  stage_half(A, lda, m0,       0,  &Als[0][0][0],   tid);
  stage_half(A, lda, m0 + 128, 0,  &Als[0][128][0], tid);
  stage_half(B, ldb, n0,       0,  &Bls[0][0][0],   tid);
  stage_half(B, ldb, n0 + 128, 0,  &Bls[0][128][0], tid);
  stage_half(B, ldb, n0,       64, &Bls[1][0][0],   tid);
  stage_half(B, ldb, n0 + 128, 64, &Bls[1][128][0], tid);
  VMC4;   // K-tile 0 complete; B(1) (4 loads) still in flight
  GBAR;

  for (int t = 0; t < NT / 2; ++t) {
    const int c = 2 * t;
    const int kc1 = ((c + 1) & (NT - 1)) * 64;
    const int kc2 = ((c + 2) & (NT - 1)) * 64;
    const int kc3 = ((c + 3) & (NT - 1)) * 64;
    // ---- K-tile c from buf0; stage A(c+1)->buf1, B(c+2)->buf0 ----
    PHASE(0, 0, stage_half(A, lda, m0,       kc1, &Als[1][0][0],   tid), (void)0);
    PHASE(0, 1, stage_half(A, lda, m0 + 128, kc1, &Als[1][128][0], tid), (void)0);
    PHASE(0, 2, stage_half(B, ldb, n0,       kc2, &Bls[0][0][0],   tid), (void)0);
    PHASE(0, 3, stage_half(B, ldb, n0 + 128, kc2, &Bls[0][128][0], tid), VMC4);
    // ---- K-tile c+1 from buf1; stage A(c+2)->buf0, B(c+3)->buf1 ----
    PHASE(1, 0, stage_half(A, lda, m0,       kc2, &Als[0][0][0],   tid), (void)0);
    PHASE(1, 1, stage_half(A, lda, m0 + 128, kc2, &Als[0][128][0], tid), (void)0);
    PHASE(1, 2, stage_half(B, ldb, n0,       kc3, &Bls[1][0][0],   tid), (void)0);
    PHASE(1, 3, stage_half(B, ldb, n0 + 128, kc3, &Bls[1][128][0], tid), VMC4);
  }
}

// ---------------- convert & concat x,h -> bf16 combined [8192][4096] ----------------

__global__ void k_convert_combined(const float* __restrict__ x,
                                   const float* __restrict__ h,
                                   bf16* __restrict__ out) {
  size_t i4 = (size_t)blockIdx.x * blockDim.x + threadIdx.x;
  size_t base = i4 * 4;
  int col = (int)(base & (KDIM - 1));
  size_t row = base >> 12;
  const float* src = (col < IN_DIM) ? (x + row * IN_DIM + col)
                                    : (h + row * (size_t)HID + (col - IN_DIM));
  float4 v = *(const float4*)src;
  union { bf16 b[4]; uint2 u; } p;
  p.b[0] = (bf16)v.x; p.b[1] = (bf16)v.y; p.b[2] = (bf16)v.z; p.b[3] = (bf16)v.w;
  *(uint2*)(out + base) = p.u;
}

// ---------------- tiled transpose + convert, 4 gates per launch ----------------

__global__ void k_tconv4(const float* __restrict__ s0, const float* __restrict__ s1,
                         const float* __restrict__ s2, const float* __restrict__ s3,
                         bf16* __restrict__ out, int nrow, int ncol,
                         long ostride, long gstride) {
  __shared__ float t[32][33];
  const float* in = blockIdx.z == 0 ? s0 : blockIdx.z == 1 ? s1
                  : blockIdx.z == 2 ? s2 : s3;
  bf16* o = out + (size_t)blockIdx.z * gstride;
  int c0 = blockIdx.x * 32, r0 = blockIdx.y * 32;
  int tx = threadIdx.x, ty = threadIdx.y;
  #pragma unroll
  for (int yy = ty; yy < 32; yy += 8)
    t[yy][tx] = in[(size_t)(r0 + yy) * ncol + c0 + tx];
  __syncthreads();
  #pragma unroll
  for (int yy = ty; yy < 32; yy += 8)
    o[(size_t)(c0 + yy) * ostride + r0 + tx] = (bf16)t[tx][yy];
}

// ---------------- GEMM1: combined @ [Ui|Uf|Uc|Uo] -> R bf16 [8192][2048] ----------------

__launch_bounds__(512, 2)
__global__ void k_gemm1(const bf16* __restrict__ A,   // [8192][4096]
                        const bf16* __restrict__ Bt,  // [2048][4096]
                        bf16* __restrict__ R) {       // [8192][2048]
  __shared__ __align__(16) bf16 Als[2][256][64];
  __shared__ __align__(16) bf16 Bls[2][256][64];
  const int bx = blockIdx.x;          // 256 blocks
  // XCD N-stripe: XCD = bx&7 owns output column stripe n0 -> B-panel (2 MB)
  // stays L2-resident with 32x reuse; A-panels are CU-private streams.
  const int n0 = (bx & 7) * 256;
  const int m0 = (bx >> 3) * 256;
  f32x4 acc[8][4];
  gemm_core<KDIM / 64>(A, KDIM, m0, Bt, KDIM, n0, Als, Bls, acc);

  const int tid = threadIdx.x;
  const int wid = tid >> 6, lane = tid & 63;
  const int wm = (wid >> 2) * 128, wn = (wid & 3) * 64;
  const int lr = lane & 15, lk = lane >> 4;
  #pragma unroll
  for (int i = 0; i < 8; ++i)
    #pragma unroll
    for (int j = 0; j < 4; ++j)
      #pragma unroll
      for (int v = 0; v < 4; ++v)
        R[(size_t)(m0 + wm + i * 16 + lk * 4 + v) * NG + (n0 + wn + j * 16 + lr)] =
            (bf16)acc[i][j][v];
}

// ---------------- gate GEMMs + activation -> G bf16 [4][CHUNK_ROWS][HID] ----------------

__launch_bounds__(512, 2)
__global__ void k_gates(const bf16* __restrict__ Rb,   // [8192][2048]
                        const bf16* __restrict__ Vt,   // [4][2048][512]
                        const float* __restrict__ b0, const float* __restrict__ b1,
                        const float* __restrict__ b2, const float* __restrict__ b3,
                        bf16* __restrict__ G, int m_base) {
  __shared__ __align__(16) bf16 Als[2][256][64];
  __shared__ __align__(16) bf16 Bls[2][256][64];
  const int bx = blockIdx.x;          // 512 blocks
  // XCD N-stripe: XCD = bx&7 owns one 256-col output stripe (all gates, all m).
  // Per-XCD B working set = 4 gates x 256x512x2B = 1 MB -> L2-resident.
  const int n0 = (bx & 7) * 256;
  const int mo = ((bx >> 3) & 15) * 256;
  const int gate = bx >> 7;           // 0..3
  f32x4 acc[8][4];
  gemm_core<RANK / 64>(Rb + gate * RANK, NG, m_base + mo,
                       Vt + (size_t)gate * HID * RANK, RANK, n0, Als, Bls, acc);

  const int tid = threadIdx.x;
  const int wid = tid >> 6, lane = tid & 63;
  const int wm = (wid >> 2) * 128, wn = (wid & 3) * 64;
  const int lr = lane & 15, lk = lane >> 4;
  const float* bias = gate == 0 ? b0 : gate == 1 ? b1 : gate == 2 ? b2 : b3;
  const bool is_tanh = (gate == 2);
  bf16* Gg = G + (size_t)gate * CHUNK_ROWS * HID;
  #pragma unroll
  for (int j = 0; j < 4; ++j) {
    const int col = n0 + wn + j * 16 + lr;
    const float bj = bias[col];
    #pragma unroll
    for (int i = 0; i < 8; ++i)
      #pragma unroll
      for (int v = 0; v < 4; ++v) {
        const int row = mo + wm + i * 16 + lk * 4 + v;
        float p = acc[i][j][v] + bj;
        float av = is_tanh ? tanhf_(p) : sigmoidf_(p);
        Gg[(size_t)row * HID + col] = (bf16)av;
      }
  }
}

// ---------------- elementwise LSTM combine ----------------

__global__ void k_ew(const bf16* __restrict__ G,
                     const float* __restrict__ cin,
                     float* __restrict__ hout, float* __restrict__ cout,
                     int m_base) {
  const size_t CHUNK = (size_t)CHUNK_ROWS * HID;
  const bf16* Gi = G;
  const bf16* Gf = G + CHUNK;
  const bf16* Gc = G + 2 * CHUNK;
  const bf16* Go = G + 3 * CHUNK;
  const size_t n8 = CHUNK / 8;
  for (size_t t = (size_t)blockIdx.x * blockDim.x + threadIdx.x; t < n8;
       t += (size_t)gridDim.x * blockDim.x) {
    size_t e = t * 8;
    bf16x8 vi = *(const bf16x8*)(Gi + e);
    bf16x8 vf = *(const bf16x8*)(Gf + e);
    bf16x8 vc = *(const bf16x8*)(Gc + e);
    bf16x8 vo = *(const bf16x8*)(Go + e);
    size_t ge = (size_t)m_base * HID + e;
    float4 c0 = *(const float4*)(cin + ge);
    float4 c1 = *(const float4*)(cin + ge + 4);
    float cc[8] = {c0.x, c0.y, c0.z, c0.w, c1.x, c1.y, c1.z, c1.w};
    float cn[8], hn[8];
    #pragma unroll
    for (int v = 0; v < 8; ++v) {
      float iv = (float)vi[v], fv = (float)vf[v], cv = (float)vc[v], ov = (float)vo[v];
      cn[v] = fv * cc[v] + iv * cv;
      hn[v] = ov * tanhf_(cn[v]);
    }
    *(float4*)(cout + ge)     = (float4){cn[0], cn[1], cn[2], cn[3]};
    *(float4*)(cout + ge + 4) = (float4){cn[4], cn[5], cn[6], cn[7]};
    *(float4*)(hout + ge)     = (float4){hn[0], hn[1], hn[2], hn[3]};
    *(float4*)(hout + ge + 4) = (float4){hn[4], hn[5], hn[6], hn[7]};
  }
}

// ---------------- launch ----------------

extern "C" void kernel_launch(void* const* d_in, const int* in_sizes, int n_in,
                              void* d_out, int out_size, void* d_ws, size_t ws_size,
                              hipStream_t stream) {
  const float* x = (const float*)d_in[0];
  const float* h = (const float*)d_in[1];
  const float* c = (const float*)d_in[2];
  const float* U[4] = {(const float*)d_in[3], (const float*)d_in[6],
                       (const float*)d_in[9], (const float*)d_in[12]};
  const float* V[4] = {(const float*)d_in[4], (const float*)d_in[7],
                       (const float*)d_in[10], (const float*)d_in[13]};
  const float* b[4] = {(const float*)d_in[5], (const float*)d_in[8],
                       (const float*)d_in[11], (const float*)d_in[14]};

  // Workspace (125,829,120 B):
  //   combined @ 0          : 67,108,864   (aliased by G after gemm1)
  //   Ut       @ 67,108,864 : 16,777,216
  //   Vt       @ 83,886,080 :  8,388,608
  //   Rbuf     @ 92,274,688 : 33,554,432
  char* ws = (char*)d_ws;
  bf16* combined = (bf16*)ws;
  bf16* Ut       = (bf16*)(ws + 67108864);
  bf16* Vt       = (bf16*)(ws + 67108864 + 16777216);
  bf16* Rbuf     = (bf16*)(ws + 67108864 + 16777216 + 8388608);
  bf16* G        = (bf16*)ws;   // aliases combined

  float* hout = (float*)d_out;
  float* cout = hout + (size_t)BATCH * HID;

  k_convert_combined<<<(BATCH * (size_t)KDIM / 4) / 256, 256, 0, stream>>>(x, h, combined);

  k_tconv4<<<dim3(RANK / 32, KDIM / 32, 4), dim3(32, 8), 0, stream>>>(
      U[0], U[1], U[2], U[3], Ut, KDIM, RANK, KDIM, (long)RANK * KDIM);
  k_tconv4<<<dim3(HID / 32, RANK / 32, 4), dim3(32, 8), 0, stream>>>(
      V[0], V[1], V[2], V[3], Vt, RANK, HID, RANK, (long)HID * RANK);

  k_gemm1<<<256, 512, 0, stream>>>(combined, Ut, Rbuf);

  for (int chunk = 0; chunk < 2; ++chunk) {
    int m_base = chunk * CHUNK_ROWS;
    k_gates<<<512, 512, 0, stream>>>(Rbuf, Vt, b[0], b[1], b[2], b[3], G, m_base);
    k_ew<<<2048, 256, 0, stream>>>(G, c, hout, cout, m_base);
  }
}

// Round 5
// 346.724 us; speedup vs baseline: 1.2716x; 1.2716x over previous
//
#include <hip/hip_runtime.h>
#include <hip/hip_bf16.h>
#include <cstdint>
#include <cstddef>

typedef __bf16 bf16;
typedef __bf16 bf16x8 __attribute__((ext_vector_type(8)));
typedef float f32x4 __attribute__((ext_vector_type(4)));

#define BATCH 8192
#define IN_DIM 2048
#define HID 2048
#define RANK 512
#define KDIM 4096    // IN+HID
#define NG 2048      // 4*RANK
#define CHUNK_ROWS 4096

// ---------------- helpers ----------------

__device__ __forceinline__ void gload16(const void* g, void* l) {
  __builtin_amdgcn_global_load_lds(
      (const __attribute__((address_space(1))) unsigned int*)g,
      (__attribute__((address_space(3))) unsigned int*)l, 16, 0, 0);
}

__device__ __forceinline__ float sigmoidf_(float x) {
  return 1.0f / (1.0f + __expf(-x));
}
__device__ __forceinline__ float tanhf_(float x) {
  return 1.0f - 2.0f / (__expf(2.0f * x) + 1.0f);
}

// Stage one 128-row x 64-col bf16 half-tile into linear LDS via global_load_lds,
// st-swizzle applied on the GLOBAL source address (inverse of the read swizzle;
// LDS dest stays linear — both-sides rule). 512 thr x 2 x 16B. vmcnt += 2/thread.
__device__ __forceinline__ void stage_half(const bf16* __restrict__ g0, int ld,
                                           int row0, int kcol, bf16* lbase, int tid) {
  const int wid = tid >> 6;
  #pragma unroll
  for (int q = 0; q < 2; ++q) {
    const int slot = q * 512 + tid;
    const int row = slot >> 3, cb = slot & 7;
    const int gcb = cb ^ (row & 7);
    gload16(g0 + (size_t)(row0 + row) * ld + kcol + gcb * 8,
            lbase + (size_t)(q * 64 + wid * 8) * 64);
  }
}

#define GBAR  __builtin_amdgcn_s_barrier()
#define LGKM0 asm volatile("s_waitcnt lgkmcnt(0)" ::: "memory")
#define VMC4  asm volatile("s_waitcnt vmcnt(4)" ::: "memory")
#define VMC8  asm volatile("s_waitcnt vmcnt(8)" ::: "memory")
#define SB0   __builtin_amdgcn_sched_barrier(0)

// Swizzled ds_reads of MFMA fragments (row&7 == lr&7 for all frag rows).
#define LD_Ap(PA, Q)                                                          \
  _Pragma("unroll") for (int ai = 0; ai < 2; ++ai)                            \
  _Pragma("unroll") for (int ks = 0; ks < 2; ++ks)                            \
    a[ai][ks] = *(const bf16x8*)((PA) + (wm + (Q) * 32 + ai * 16 + lr) * 64   \
                                 + ((((ks << 2) | lk) ^ sw) << 3));

#define LD_Bp(PB)                                                             \
  _Pragma("unroll") for (int j = 0; j < 4; ++j)                               \
  _Pragma("unroll") for (int ks = 0; ks < 2; ++ks)                            \
    b[j][ks] = *(const bf16x8*)((PB) + (wn + j * 16 + lr) * 64                \
                                 + ((((ks << 2) | lk) ^ sw) << 3));

#define MFMAQ(Q)                                                              \
  _Pragma("unroll") for (int ai = 0; ai < 2; ++ai)                            \
  _Pragma("unroll") for (int ks = 0; ks < 2; ++ks)                            \
  _Pragma("unroll") for (int j = 0; j < 4; ++j)                               \
    acc[(Q) * 2 + ai][j] = __builtin_amdgcn_mfma_f32_16x16x32_bf16(           \
        a[ai][ks], b[j][ks], acc[(Q) * 2 + ai][j], 0, 0, 0);

// Phase: [TOP reads] / stage / barrier / lgkm0 / MFMA / prefetch next phase's
// ds_reads (overlaps next barrier+stage window) / [vmcnt] / barrier.
#define PHASE3(TOP, STAGE, Q, PFOP, TAILVM) \
  {                                         \
    TOP;                                    \
    STAGE;                                  \
    GBAR;                                   \
    LGKM0;                                  \
    __builtin_amdgcn_s_setprio(1);          \
    MFMAQ(Q);                               \
    __builtin_amdgcn_s_setprio(0);          \
    PFOP;                                   \
    SB0;                                    \
    TAILVM;                                 \
    GBAR;                                   \
  }

// 256x256 tile, BK=64, 8 waves (2M x 4N). A double-buffered (2x32KB),
// B TRIPLE-buffered (3x32KB) => 160 KB LDS. 4 phases/K-tile, all fragment
// ds_reads issued one phase ahead; counted vmcnt(4) once per K-tile.
// NT = K/64 (power of two, >= 4).
template <int NT>
__device__ __forceinline__ void gemm_core(const bf16* __restrict__ A, int lda, int m0,
                                          const bf16* __restrict__ B, int ldb, int n0,
                                          bf16* lds, f32x4 (&acc)[8][4]) {
  const int tid = threadIdx.x;
  const int wid = tid >> 6, lane = tid & 63;
  const int wm = (wid >> 2) * 128, wn = (wid & 3) * 64;
  const int lr = lane & 15, lk = lane >> 4;
  const int sw = lr & 7;
  bf16x8 a[2][2], b[4][2];

  bf16* Ab0 = lds;                 // 256*64 = 16384 elems = 32 KB
  bf16* Ab1 = lds + 16384;
  bf16* Rg0 = lds + 2 * 16384;     // B ring
  bf16* Rg1 = lds + 3 * 16384;
  bf16* Rg2 = lds + 4 * 16384;

  #pragma unroll
  for (int i = 0; i < 8; ++i)
    #pragma unroll
    for (int j = 0; j < 4; ++j) acc[i][j] = (f32x4){0.f, 0.f, 0.f, 0.f};

  // Prologue: A(0)->Ab0, B(0)->Rg0, B(1)->Rg1, B(2)->Rg2. 16 loads/thread.
  stage_half(A, lda, m0,       0,   Ab0,        tid);
  stage_half(A, lda, m0 + 128, 0,   Ab0 + 8192, tid);
  stage_half(B, ldb, n0,       0,   Rg0,        tid);
  stage_half(B, ldb, n0 + 128, 0,   Rg0 + 8192, tid);
  stage_half(B, ldb, n0,       64,  Rg1,        tid);
  stage_half(B, ldb, n0 + 128, 64,  Rg1 + 8192, tid);
  stage_half(B, ldb, n0,       128, Rg2,        tid);
  stage_half(B, ldb, n0 + 128, 128, Rg2 + 8192, tid);
  VMC8;   // A(0), B(0) complete; B(1), B(2) (8 loads) still in flight
  GBAR;
  LD_Bp(Rg0);   // preload B(0) fragments (drained at tile-0 Q0's lgkm0)

  bf16 *pBc = Rg0, *pBn = Rg1, *pBn2 = Rg2;   // B(c), B(c+1), B(c+2)
  bf16 *pAc = Ab0, *pAa = Ab1;
  for (int c = 0; c < NT; ++c) {
    const int kc1 = ((c + 1) & (NT - 1)) * 64;
    const int kc3 = ((c + 3) & (NT - 1)) * 64;
    PHASE3(LD_Ap(pAc, 0), stage_half(A, lda, m0,       kc1, pAa,        tid), 0,
           LD_Ap(pAc, 1), (void)0);
    PHASE3((void)0,       stage_half(A, lda, m0 + 128, kc1, pAa + 8192, tid), 1,
           LD_Ap(pAc, 2), (void)0);
    PHASE3((void)0,       stage_half(B, ldb, n0,       kc3, pBc,        tid), 2,
           LD_Ap(pAc, 3), (void)0);
    PHASE3((void)0,       stage_half(B, ldb, n0 + 128, kc3, pBc + 8192, tid), 3,
           LD_Bp(pBn),    VMC4);
    bf16* tt = pBc; pBc = pBn; pBn = pBn2; pBn2 = tt;   // rotate B ring
    tt = pAc; pAc = pAa; pAa = tt;                      // swap A buffers
  }
}

// ---------------- convert & concat x,h -> bf16 combined [8192][4096] ----------------

__global__ void k_convert_combined(const float* __restrict__ x,
                                   const float* __restrict__ h,
                                   bf16* __restrict__ out) {
  size_t i4 = (size_t)blockIdx.x * blockDim.x + threadIdx.x;
  size_t base = i4 * 4;
  int col = (int)(base & (KDIM - 1));
  size_t row = base >> 12;
  const float* src = (col < IN_DIM) ? (x + row * IN_DIM + col)
                                    : (h + row * (size_t)HID + (col - IN_DIM));
  float4 v = *(const float4*)src;
  union { bf16 b[4]; uint2 u; } p;
  p.b[0] = (bf16)v.x; p.b[1] = (bf16)v.y; p.b[2] = (bf16)v.z; p.b[3] = (bf16)v.w;
  *(uint2*)(out + base) = p.u;
}

// ---------------- tiled transpose + convert, 4 gates per launch ----------------

__global__ void k_tconv4(const float* __restrict__ s0, const float* __restrict__ s1,
                         const float* __restrict__ s2, const float* __restrict__ s3,
                         bf16* __restrict__ out, int nrow, int ncol,
                         long ostride, long gstride) {
  __shared__ float t[32][33];
  const float* in = blockIdx.z == 0 ? s0 : blockIdx.z == 1 ? s1
                  : blockIdx.z == 2 ? s2 : s3;
  bf16* o = out + (size_t)blockIdx.z * gstride;
  int c0 = blockIdx.x * 32, r0 = blockIdx.y * 32;
  int tx = threadIdx.x, ty = threadIdx.y;
  #pragma unroll
  for (int yy = ty; yy < 32; yy += 8)
    t[yy][tx] = in[(size_t)(r0 + yy) * ncol + c0 + tx];
  __syncthreads();
  #pragma unroll
  for (int yy = ty; yy < 32; yy += 8)
    o[(size_t)(c0 + yy) * ostride + r0 + tx] = (bf16)t[tx][yy];
}

// ---------------- GEMM1: combined @ [Ui|Uf|Uc|Uo] -> R bf16 [8192][2048] ----------------

__launch_bounds__(512, 2)
__global__ void k_gemm1(const bf16* __restrict__ A,   // [8192][4096]
                        const bf16* __restrict__ Bt,  // [2048][4096]
                        bf16* __restrict__ R) {       // [8192][2048]
  __shared__ __align__(16) bf16 lds[81920];   // 160 KB
  const int bx = blockIdx.x;                  // 256 blocks
  const int id = (bx & 7) * 32 + (bx >> 3);   // round-3 XCD-bijective swizzle
  const int m0 = (id >> 3) * 256, n0 = (id & 7) * 256;
  f32x4 acc[8][4];
  gemm_core<KDIM / 64>(A, KDIM, m0, Bt, KDIM, n0, lds, acc);

  const int tid = threadIdx.x;
  const int wid = tid >> 6, lane = tid & 63;
  const int wm = (wid >> 2) * 128, wn = (wid & 3) * 64;
  const int lr = lane & 15, lk = lane >> 4;
  #pragma unroll
  for (int i = 0; i < 8; ++i)
    #pragma unroll
    for (int j = 0; j < 4; ++j)
      #pragma unroll
      for (int v = 0; v < 4; ++v)
        R[(size_t)(m0 + wm + i * 16 + lk * 4 + v) * NG + (n0 + wn + j * 16 + lr)] =
            (bf16)acc[i][j][v];
}

// ---------------- gate GEMMs + activation -> G bf16 [4][CHUNK_ROWS][HID] ----------------

__launch_bounds__(512, 2)
__global__ void k_gates(const bf16* __restrict__ Rb,   // [8192][2048]
                        const bf16* __restrict__ Vt,   // [4][2048][512]
                        const float* __restrict__ b0, const float* __restrict__ b1,
                        const float* __restrict__ b2, const float* __restrict__ b3,
                        bf16* __restrict__ G, int m_base) {
  __shared__ __align__(16) bf16 lds[81920];   // 160 KB
  const int bx = blockIdx.x;                  // 512 blocks
  const int id = (bx & 7) * 64 + (bx >> 3);   // round-3 XCD-bijective swizzle
  const int gate = id >> 7;                   // 0..3
  const int mo = ((id >> 3) & 15) * 256;      // row within chunk
  const int n0 = (id & 7) * 256;
  f32x4 acc[8][4];
  gemm_core<RANK / 64>(Rb + gate * RANK, NG, m_base + mo,
                       Vt + (size_t)gate * HID * RANK, RANK, n0, lds, acc);

  const int tid = threadIdx.x;
  const int wid = tid >> 6, lane = tid & 63;
  const int wm = (wid >> 2) * 128, wn = (wid & 3) * 64;
  const int lr = lane & 15, lk = lane >> 4;
  const float* bias = gate == 0 ? b0 : gate == 1 ? b1 : gate == 2 ? b2 : b3;
  const bool is_tanh = (gate == 2);
  bf16* Gg = G + (size_t)gate * CHUNK_ROWS * HID;
  #pragma unroll
  for (int j = 0; j < 4; ++j) {
    const int col = n0 + wn + j * 16 + lr;
    const float bj = bias[col];
    #pragma unroll
    for (int i = 0; i < 8; ++i)
      #pragma unroll
      for (int v = 0; v < 4; ++v) {
        const int row = mo + wm + i * 16 + lk * 4 + v;
        float p = acc[i][j][v] + bj;
        float av = is_tanh ? tanhf_(p) : sigmoidf_(p);
        Gg[(size_t)row * HID + col] = (bf16)av;
      }
  }
}

// ---------------- elementwise LSTM combine ----------------

__global__ void k_ew(const bf16* __restrict__ G,
                     const float* __restrict__ cin,
                     float* __restrict__ hout, float* __restrict__ cout,
                     int m_base) {
  const size_t CHUNK = (size_t)CHUNK_ROWS * HID;
  const bf16* Gi = G;
  const bf16* Gf = G + CHUNK;
  const bf16* Gc = G + 2 * CHUNK;
  const bf16* Go = G + 3 * CHUNK;
  const size_t n8 = CHUNK / 8;
  for (size_t t = (size_t)blockIdx.x * blockDim.x + threadIdx.x; t < n8;
       t += (size_t)gridDim.x * blockDim.x) {
    size_t e = t * 8;
    bf16x8 vi = *(const bf16x8*)(Gi + e);
    bf16x8 vf = *(const bf16x8*)(Gf + e);
    bf16x8 vc = *(const bf16x8*)(Gc + e);
    bf16x8 vo = *(const bf16x8*)(Go + e);
    size_t ge = (size_t)m_base * HID + e;
    float4 c0 = *(const float4*)(cin + ge);
    float4 c1 = *(const float4*)(cin + ge + 4);
    float cc[8] = {c0.x, c0.y, c0.z, c0.w, c1.x, c1.y, c1.z, c1.w};
    float cn[8], hn[8];
    #pragma unroll
    for (int v = 0; v < 8; ++v) {
      float iv = (float)vi[v], fv = (float)vf[v], cv = (float)vc[v], ov = (float)vo[v];
      cn[v] = fv * cc[v] + iv * cv;
      hn[v] = ov * tanhf_(cn[v]);
    }
    *(float4*)(cout + ge)     = (float4){cn[0], cn[1], cn[2], cn[3]};
    *(float4*)(cout + ge + 4) = (float4){cn[4], cn[5], cn[6], cn[7]};
    *(float4*)(hout + ge)     = (float4){hn[0], hn[1], hn[2], hn[3]};
    *(float4*)(hout + ge + 4) = (float4){hn[4], hn[5], hn[6], hn[7]};
  }
}

// ---------------- launch ----------------

extern "C" void kernel_launch(void* const* d_in, const int* in_sizes, int n_in,
                              void* d_out, int out_size, void* d_ws, size_t ws_size,
                              hipStream_t stream) {
  const float* x = (const float*)d_in[0];
  const float* h = (const float*)d_in[1];
  const float* c = (const float*)d_in[2];
  const float* U[4] = {(const float*)d_in[3], (const float*)d_in[6],
                       (const float*)d_in[9], (const float*)d_in[12]};
  const float* V[4] = {(const float*)d_in[4], (const float*)d_in[7],
                       (const float*)d_in[10], (const float*)d_in[13]};
  const float* b[4] = {(const float*)d_in[5], (const float*)d_in[8],
                       (const float*)d_in[11], (const float*)d_in[14]};

  // Workspace (125,829,120 B):
  //   combined @ 0          : 67,108,864   (aliased by G after gemm1)
  //   Ut       @ 67,108,864 : 16,777,216
  //   Vt       @ 83,886,080 :  8,388,608
  //   Rbuf     @ 92,274,688 : 33,554,432
  char* ws = (char*)d_ws;
  bf16* combined = (bf16*)ws;
  bf16* Ut       = (bf16*)(ws + 67108864);
  bf16* Vt       = (bf16*)(ws + 67108864 + 16777216);
  bf16* Rbuf     = (bf16*)(ws + 67108864 + 16777216 + 8388608);
  bf16* G        = (bf16*)ws;   // aliases combined

  float* hout = (float*)d_out;
  float* cout = hout + (size_t)BATCH * HID;

  k_convert_combined<<<(BATCH * (size_t)KDIM / 4) / 256, 256, 0, stream>>>(x, h, combined);

  k_tconv4<<<dim3(RANK / 32, KDIM / 32, 4), dim3(32, 8), 0, stream>>>(
      U[0], U[1], U[2], U[3], Ut, KDIM, RANK, KDIM, (long)RANK * KDIM);
  k_tconv4<<<dim3(HID / 32, RANK / 32, 4), dim3(32, 8), 0, stream>>>(
      V[0], V[1], V[2], V[3], Vt, RANK, HID, RANK, (long)HID * RANK);

  k_gemm1<<<256, 512, 0, stream>>>(combined, Ut, Rbuf);

  for (int chunk = 0; chunk < 2; ++chunk) {
    int m_base = chunk * CHUNK_ROWS;
    k_gates<<<512, 512, 0, stream>>>(Rbuf, Vt, b[0], b[1], b[2], b[3], G, m_base);
    k_ew<<<2048, 256, 0, stream>>>(G, c, hout, cout, m_base);
  }
}